// Round 1
// baseline (1268.673 us; speedup 1.0000x reference)
//
#include <hip/hip_runtime.h>

#define HID 128
#define NNODE 50000
#define NEDGE 640000

// ---------------------------------------------------------------- embed: x = emb[z]
static __global__ void embed_kernel(const int* __restrict__ z,
                                    const float* __restrict__ emb,
                                    float* __restrict__ x) {
  int i = blockIdx.x * 256 + threadIdx.x;          // over NNODE*32 float4 groups
  const int total = NNODE * (HID / 4);
  if (i >= total) return;
  int node = i >> 5;
  int c = i & 31;
  ((float4*)x)[i] = ((const float4*)emb)[(size_t)z[node] * 32 + c];
}

// ---------------------------------------------------------------- CSR build
static __global__ void hist_kernel(const int* __restrict__ dst, int* __restrict__ deg) {
  int i = blockIdx.x * 256 + threadIdx.x;
  if (i < NEDGE) atomicAdd(&deg[dst[i]], 1);
}

static __global__ void scan_kernel(const int* __restrict__ deg,
                                   int* __restrict__ row_ptr,
                                   int* __restrict__ cursor) {
  __shared__ int sums[1024];
  int t = threadIdx.x;
  const int per = (NNODE + 1023) / 1024;           // 49
  int base = t * per;
  int s = 0;
  for (int i = 0; i < per; ++i) {
    int idx = base + i;
    if (idx < NNODE) s += deg[idx];
  }
  sums[t] = s;
  __syncthreads();
  for (int off = 1; off < 1024; off <<= 1) {
    int v = (t >= off) ? sums[t - off] : 0;
    __syncthreads();
    if (t >= off) sums[t] += v;
    __syncthreads();
  }
  int run = (t == 0) ? 0 : sums[t - 1];            // exclusive prefix
  for (int i = 0; i < per; ++i) {
    int idx = base + i;
    if (idx < NNODE) {
      row_ptr[idx] = run;
      cursor[idx] = run;
      run += deg[idx];
    }
  }
  if (t == 1023) row_ptr[NNODE] = run;             // == NEDGE
}

static __global__ void fill_kernel(const int* __restrict__ src, const int* __restrict__ dst,
                                   int* __restrict__ cursor, int2* __restrict__ elist) {
  int i = blockIdx.x * 256 + threadIdx.x;
  if (i < NEDGE) {
    int d = dst[i];
    int p = atomicAdd(&cursor[d], 1);
    elist[p] = make_int2(i, src[i]);               // (edge id, src node)
  }
}

// ---------------------------------------------------------------- gather: out = x + sum_{e->n} relu(x[src]+ea[e])
static __global__ __launch_bounds__(256) void gather_kernel(
    const float* __restrict__ x, const float* __restrict__ ea,
    const int* __restrict__ row_ptr, const int2* __restrict__ elist,
    float* __restrict__ out) {
  int wave = threadIdx.x >> 6;                     // 4 waves/block, 1 node/wave
  int lane = threadIdx.x & 63;
  int node = blockIdx.x * 4 + wave;
  if (node >= NNODE) return;
  const float2* x2 = (const float2*)x;
  const float2* e2 = (const float2*)ea;
  float2 acc = x2[(size_t)node * 64 + lane];       // out = agg + x : init with x
  int je = row_ptr[node + 1];
  for (int j = row_ptr[node]; j < je; ++j) {
    int2 es = elist[j];                            // wave-uniform
    float2 xv = x2[(size_t)es.y * 64 + lane];
    float2 ev = e2[(size_t)es.x * 64 + lane];
    float a0 = xv.x + ev.x, a1 = xv.y + ev.y;
    acc.x += fmaxf(a0, 0.f);
    acc.y += fmaxf(a1, 0.f);
  }
  ((float2*)out)[(size_t)node * 64 + lane] = acc;
}

// ---------------------------------------------------------------- MLP: xout = x + [relu?](relu(in@W1+b1)@W2+b2)
// 64-row tile per block; W in LDS; 4x8 register block per thread.
static __global__ __launch_bounds__(256) void mlp_kernel(
    const float* __restrict__ in, const float* __restrict__ xres,
    const float* __restrict__ W1, const float* __restrict__ b1,
    const float* __restrict__ W2, const float* __restrict__ b2,
    float* __restrict__ xout, int relu_out) {
  __shared__ float As[64 * 132];                   // ld=132: pad kills bank conflicts
  __shared__ float Ws[128 * 128];
  const int tid = threadIdx.x;
  const int row0 = blockIdx.x * 64;

  // stage A tile (zeros for tail rows)
  for (int i = tid; i < 64 * 32; i += 256) {
    int r = i >> 5, c = i & 31;
    float4 v = make_float4(0.f, 0.f, 0.f, 0.f);
    int row = row0 + r;
    if (row < NNODE) v = ((const float4*)in)[(size_t)row * 32 + c];
    *(float4*)&As[r * 132 + c * 4] = v;
  }
  // stage W1
  for (int i = tid; i < 128 * 32; i += 256)
    ((float4*)Ws)[i] = ((const float4*)W1)[i];
  __syncthreads();

  const int rg = tid >> 4, cg = tid & 15;
  const int rb = rg * 4, cb = cg * 8;

  float acc[4][8];
#pragma unroll
  for (int r = 0; r < 4; ++r)
#pragma unroll
    for (int c = 0; c < 8; ++c) acc[r][c] = 0.f;

  // ---- GEMM 1: t = relu(A @ W1 + b1)
  for (int k = 0; k < 128; k += 4) {
    float4 a0 = *(const float4*)&As[(rb + 0) * 132 + k];
    float4 a1 = *(const float4*)&As[(rb + 1) * 132 + k];
    float4 a2 = *(const float4*)&As[(rb + 2) * 132 + k];
    float4 a3 = *(const float4*)&As[(rb + 3) * 132 + k];
#pragma unroll
    for (int kk = 0; kk < 4; ++kk) {
      float4 w0 = *(const float4*)&Ws[(k + kk) * 128 + cb];
      float4 w1 = *(const float4*)&Ws[(k + kk) * 128 + cb + 4];
      float av[4] = {((const float*)&a0)[kk], ((const float*)&a1)[kk],
                     ((const float*)&a2)[kk], ((const float*)&a3)[kk]};
#pragma unroll
      for (int r = 0; r < 4; ++r) {
        acc[r][0] += av[r] * w0.x; acc[r][1] += av[r] * w0.y;
        acc[r][2] += av[r] * w0.z; acc[r][3] += av[r] * w0.w;
        acc[r][4] += av[r] * w1.x; acc[r][5] += av[r] * w1.y;
        acc[r][6] += av[r] * w1.z; acc[r][7] += av[r] * w1.w;
      }
    }
  }
  __syncthreads();                                  // all phase-1 LDS reads done

  // write t into As; stage W2
#pragma unroll
  for (int r = 0; r < 4; ++r) {
    float t0[8];
#pragma unroll
    for (int c = 0; c < 8; ++c) {
      float v = acc[r][c] + b1[cb + c];
      t0[c] = fmaxf(v, 0.f);
    }
    *(float4*)&As[(rb + r) * 132 + cb]     = make_float4(t0[0], t0[1], t0[2], t0[3]);
    *(float4*)&As[(rb + r) * 132 + cb + 4] = make_float4(t0[4], t0[5], t0[6], t0[7]);
  }
  for (int i = tid; i < 128 * 32; i += 256)
    ((float4*)Ws)[i] = ((const float4*)W2)[i];
  __syncthreads();

#pragma unroll
  for (int r = 0; r < 4; ++r)
#pragma unroll
    for (int c = 0; c < 8; ++c) acc[r][c] = 0.f;

  // ---- GEMM 2: h = t @ W2 + b2
  for (int k = 0; k < 128; k += 4) {
    float4 a0 = *(const float4*)&As[(rb + 0) * 132 + k];
    float4 a1 = *(const float4*)&As[(rb + 1) * 132 + k];
    float4 a2 = *(const float4*)&As[(rb + 2) * 132 + k];
    float4 a3 = *(const float4*)&As[(rb + 3) * 132 + k];
#pragma unroll
    for (int kk = 0; kk < 4; ++kk) {
      float4 w0 = *(const float4*)&Ws[(k + kk) * 128 + cb];
      float4 w1 = *(const float4*)&Ws[(k + kk) * 128 + cb + 4];
      float av[4] = {((const float*)&a0)[kk], ((const float*)&a1)[kk],
                     ((const float*)&a2)[kk], ((const float*)&a3)[kk]};
#pragma unroll
      for (int r = 0; r < 4; ++r) {
        acc[r][0] += av[r] * w0.x; acc[r][1] += av[r] * w0.y;
        acc[r][2] += av[r] * w0.z; acc[r][3] += av[r] * w0.w;
        acc[r][4] += av[r] * w1.x; acc[r][5] += av[r] * w1.y;
        acc[r][6] += av[r] * w1.z; acc[r][7] += av[r] * w1.w;
      }
    }
  }

  // epilogue: bias, optional relu, residual, store
#pragma unroll
  for (int r = 0; r < 4; ++r) {
    int row = row0 + rb + r;
    if (row < NNODE) {
      float4 xv0 = ((const float4*)xres)[(size_t)row * 32 + (cb >> 2)];
      float4 xv1 = ((const float4*)xres)[(size_t)row * 32 + (cb >> 2) + 1];
      float o[8];
#pragma unroll
      for (int c = 0; c < 8; ++c) {
        float v = acc[r][c] + b2[cb + c];
        if (relu_out) v = fmaxf(v, 0.f);
        o[c] = v;
      }
      o[0] += xv0.x; o[1] += xv0.y; o[2] += xv0.z; o[3] += xv0.w;
      o[4] += xv1.x; o[5] += xv1.y; o[6] += xv1.z; o[7] += xv1.w;
      ((float4*)xout)[(size_t)row * 32 + (cb >> 2)]     = make_float4(o[0], o[1], o[2], o[3]);
      ((float4*)xout)[(size_t)row * 32 + (cb >> 2) + 1] = make_float4(o[4], o[5], o[6], o[7]);
    }
  }
}

extern "C" void kernel_launch(void* const* d_in, const int* in_sizes, int n_in,
                              void* d_out, int out_size, void* d_ws, size_t ws_size,
                              hipStream_t stream) {
  const int*   z   = (const int*)d_in[0];
  const int*   ei  = (const int*)d_in[1];     // [2, E] row-major
  const float* ea  = (const float*)d_in[2];
  const float* emb = (const float*)d_in[3];
  const float* W1  = (const float*)d_in[4];
  const float* b1  = (const float*)d_in[5];
  const float* W2  = (const float*)d_in[6];
  const float* b2  = (const float*)d_in[7];
  float* outp = (float*)d_out;

  char* ws = (char*)d_ws;
  float* xbuf   = (float*)(ws + 0);            // 25,600,000 B
  float* obuf   = (float*)(ws + 25600000);     // 25,600,000 B
  int*   deg    = (int*)  (ws + 51200000);     //    200,000 B
  int*   cursor = (int*)  (ws + 51400000);     //    200,000 B
  int*   rowptr = (int*)  (ws + 51600000);     //    200,004 B
  int2*  elist  = (int2*) (ws + 51800016);     //  5,120,000 B  (end ~56.9 MB)

  const int* srcv = ei;
  const int* dstv = ei + NEDGE;

  hipMemsetAsync(deg, 0, NNODE * sizeof(int), stream);
  embed_kernel<<<(NNODE * 32 + 255) / 256, 256, 0, stream>>>(z, emb, xbuf);
  hist_kernel<<<(NEDGE + 255) / 256, 256, 0, stream>>>(dstv, deg);
  scan_kernel<<<1, 1024, 0, stream>>>(deg, rowptr, cursor);
  fill_kernel<<<(NEDGE + 255) / 256, 256, 0, stream>>>(srcv, dstv, cursor, elist);

  for (int i = 0; i < 3; ++i) {
    gather_kernel<<<(NNODE + 3) / 4, 256, 0, stream>>>(xbuf, ea, rowptr, elist, obuf);
    float* xo = (i == 2) ? outp : xbuf;
    mlp_kernel<<<(NNODE + 63) / 64, 256, 0, stream>>>(
        obuf, xbuf,
        W1 + (size_t)i * HID * HID, b1 + (size_t)i * HID,
        W2 + (size_t)i * HID * HID, b2 + (size_t)i * HID,
        xo, (i < 2) ? 1 : 0);
  }
}